// Round 11
// baseline (77.430 us; speedup 1.0000x reference)
//
#include <hip/hip_runtime.h>
#include <hip/hip_bf16.h>

// DeformConv2d: x[4,4,256,36,36] f32, filter[1024,256,3,3] f32, offset[16,2] f32
// out[4,1024,36,36] f32.
// R11 = R8 (bf16, proven) with gemm re-tiled 128x64 -> 128x128 (wave-tile 64x64,
// acc 4x4): 32 MFMA/iter/wave amortizes the fixed stage+vmcnt+barrier cost that
// capped the 2-phase structure. Same counted-vmcnt sync skeleton. f16 branch
// closed (R9/R10: identical structural failure -> f16 MFMA A/B layout unverified).
// K layout k' = n*256+c. ws = 100,270,080 B.

#define HH 36
#define WW 36
#define CT 256
#define NB 16
#define KK 2304      // 9*256
#define NP 1296      // 36*36
#define OCH 1024
#define OUTG 256

typedef __attribute__((ext_vector_type(8))) short short8;
typedef __attribute__((ext_vector_type(4))) float f32x4;
typedef __attribute__((ext_vector_type(4))) unsigned short us4;
typedef __attribute__((ext_vector_type(4))) unsigned uint4v;

__device__ __forceinline__ unsigned short f2bf(float v) {
    unsigned u = __float_as_uint(v);
    u += 0x7fffu + ((u >> 16) & 1u);   // RNE
    return (unsigned short)(u >> 16);
}
__device__ __forceinline__ unsigned pk2bf(float lo, float hi) {
    __hip_bfloat162 h = __float22bfloat162_rn(float2{lo, hi});   // v_cvt_pk_bf16_f32
    return *reinterpret_cast<unsigned*>(&h);
}

// ---------------- kernel 1: filter fp32 [o][c*9+n] -> bf16 [o][n*256+c] ----------
__global__ __launch_bounds__(256) void cvt_filter(const float* __restrict__ f,
                                                  unsigned short* __restrict__ w) {
    const int o = blockIdx.x;
    const float* fo = f + (size_t)o * KK;
    unsigned short* wo = w + (size_t)o * KK;
    for (int k4 = threadIdx.x * 4; k4 < KK; k4 += 1024) {
        int n = k4 >> 8;          // tap
        int c = k4 & 255;         // channel (multiple of 4)
        us4 v;
#pragma unroll
        for (int cc = 0; cc < 4; ++cc) v[cc] = f2bf(fo[(c + cc) * 9 + n]);
        *reinterpret_cast<us4*>(wo + k4) = v;
    }
}

// ---------------- kernel 2: deformable bilinear sampling -> Xoff^T bf16 -----------
// grid 1152 = 16b * 36y * 2 half(128ch), XCD-swizzled (2 b per XCD, matches gemm).
__global__ __launch_bounds__(256) void sample_kernel(const float* __restrict__ x,
                                                     const float* __restrict__ off,
                                                     unsigned short* __restrict__ xt) {
    const int wid = (blockIdx.x & 7) * 144 + (blockIdx.x >> 3);
    const int b = wid / 72;
    const int rem = wid - b * 72;
    const int y = rem >> 1;
    const int half = rem & 1;
    const int tid = threadIdx.x;
    const float sx = 3.0f / off[2 * b + 0];
    const float sy = 3.0f / off[2 * b + 1];

    // row (i) tables: per-thread registers (block-uniform)
    int qxl[3], qxr[3]; float gxl[3], gxr[3];
    bool lok[3], rok[3];
#pragma unroll
    for (int i = 0; i < 3; ++i) {
        float px = (float)(y + 1) + (float)(i - 1) * sx;
        float pc = fminf(fmaxf(px, 0.f), 37.f);
        float fl = floorf(px);
        float ql = fminf(fmaxf(fl, 0.f), 37.f);
        float qr = fminf(fmaxf(fl + 1.f, 0.f), 37.f);
        qxl[i] = (int)ql; qxr[i] = (int)qr;
        gxl[i] = 1.f + (ql - pc);
        gxr[i] = 1.f - (qr - pc);
        lok[i] = (qxl[i] >= 1 && qxl[i] <= 36);
        rok[i] = (qxr[i] >= 1 && qxr[i] <= 36);
    }

    // column (x,j) tables in LDS
    __shared__ int   s_qyl[HH * 3], s_qyr[HH * 3];
    __shared__ float s_gyl[HH * 3], s_gyr[HH * 3];
    if (tid < HH * 3) {
        int xx = tid / 3, j = tid % 3;
        float py = (float)(xx + 1) + (float)(j - 1) * sy;
        float pc = fminf(fmaxf(py, 0.f), 37.f);
        float fl = floorf(py);
        float ql = fminf(fmaxf(fl, 0.f), 37.f);
        float qr = fminf(fmaxf(fl + 1.f, 0.f), 37.f);
        s_qyl[tid] = (int)ql; s_qyr[tid] = (int)qr;
        s_gyl[tid] = 1.f + (ql - pc);
        s_gyr[tid] = 1.f - (qr - pc);
    }

    // row-lerped tile, c-contiguous: xr[i][col 0..37][c 0..63] f32 (29.2 KB)
    __shared__ float xr[3 * 38 * 64];

    for (int chunk = 0; chunk < 2; ++chunk) {
        const int c0 = half * 128 + chunk * 64;
        __syncthreads();      // xr reusable (prev phase-2 done); covers tables iter0

        // boundary cols 0 and 37 are zero (zero padding)
        for (int t = tid; t < 384; t += 256) {
            int i = t / 128, r3 = t & 127;
            int col = (r3 & 64) ? 37 : 0, c = r3 & 63;
            xr[(i * 38 + col) * 64 + c] = 0.f;
        }

        // phase 1: row-lerp. tasks (i, c, colquad): coalesced float4 col-reads,
        // 4 scalar LDS writes (stride 256B) per task.
        const float* xb = x + (size_t)(b * CT + c0) * NP;
        for (int t = tid; t < 3 * 64 * 9; t += 256) {
            const int i = t / 576;
            const int r2 = t - i * 576;
            const int c = r2 / 9;
            const int cq = r2 - c * 9;
            const int colb = 1 + cq * 4;          // padded col of elem 0
            const float* xc = xb + c * NP;
            float4 vl = make_float4(0.f, 0.f, 0.f, 0.f);
            float4 vr = vl;
            if (lok[i]) vl = *(const float4*)(xc + (qxl[i] - 1) * WW + colb - 1);
            if (rok[i]) vr = *(const float4*)(xc + (qxr[i] - 1) * WW + colb - 1);
            float* dst = &xr[(i * 38 + colb) * 64 + c];
            dst[0]   = gxl[i] * vl.x + gxr[i] * vr.x;
            dst[64]  = gxl[i] * vl.y + gxr[i] * vr.y;
            dst[128] = gxl[i] * vl.z + gxr[i] * vr.z;
            dst[192] = gxl[i] * vl.w + gxr[i] * vr.w;
        }
        __syncthreads();

        // phase 2: column-lerp + pack. tasks (xi, c8): 9 taps x 8 channels each.
        for (int t = tid; t < 36 * 8; t += 256) {
            const int xi = t >> 3;
            const int c8 = t & 7;
            unsigned short* op = xt + ((size_t)b * NP + y * WW + xi) * KK + c0 + c8 * 8;
#pragma unroll
            for (int n = 0; n < 9; ++n) {
                const int i = n / 3, j = n - i * 3;
                const int tq = xi * 3 + j;
                const float gl = s_gyl[tq], gr = s_gyr[tq];
                const float* L = &xr[(i * 38 + s_qyl[tq]) * 64 + c8 * 8];
                const float* R = &xr[(i * 38 + s_qyr[tq]) * 64 + c8 * 8];
                f32x4 L0 = *(const f32x4*)L, L1 = *(const f32x4*)(L + 4);
                f32x4 R0 = *(const f32x4*)R, R1 = *(const f32x4*)(R + 4);
                uint4v w;
                w[0] = pk2bf(gl * L0[0] + gr * R0[0], gl * L0[1] + gr * R0[1]);
                w[1] = pk2bf(gl * L0[2] + gr * R0[2], gl * L0[3] + gr * R0[3]);
                w[2] = pk2bf(gl * L1[0] + gr * R1[0], gl * L1[1] + gr * R1[1]);
                w[3] = pk2bf(gl * L1[2] + gr * R1[2], gl * L1[3] + gr * R1[3]);
                *reinterpret_cast<uint4v*>(op + n * 256) = w;
            }
        }
    }
}

// ---------------- kernel 3: MFMA GEMM, 128x128 tile, 64x64/wave, counted vmcnt ----
__global__ __launch_bounds__(256) void gemm_kernel(const unsigned short* __restrict__ wbf,
                                                   const unsigned short* __restrict__ xt,
                                                   float* __restrict__ out) {
    // 352 blocks = 8 XCD * 44; 44 per XCD = 2 b's worth (22 tiles per b)
    const int wid = (blockIdx.x & 7) * 44 + (blockIdx.x >> 3);
    const int b = wid / 22;
    const int rem = wid - b * 22;
    const int mt = rem / 11;
    const int nt = rem - mt * 11;
    const int m0 = mt * 128;
    const int p0 = nt * 128;
    const int g = b & 3;
    const int mimg = b >> 2;

    const unsigned short* Ab = wbf + (size_t)(g * OUTG + m0) * KK;
    const unsigned short* Bb = xt + (size_t)b * NP * KK;

    __shared__ __align__(16) unsigned short As[2][128 * 64];   // 32 KB
    __shared__ __align__(16) unsigned short Bs[2][128 * 64];   // 32 KB

    const int tid = threadIdx.x;
    const int wave = tid >> 6, lane = tid & 63;
    const int wr = wave >> 1, wc = wave & 1;
    const int l8 = lane >> 3;
    const int sgrp = (lane & 7) ^ l8;         // pre-swizzled source column group

    f32x4 acc[4][4] = {};

#define STAGE(BUF, KT) do {                                                       \
    const int k0_ = (KT) * 64;                                                    \
    _Pragma("unroll")                                                             \
    for (int ii = 0; ii < 4; ++ii) {                                              \
        const int inst = wave * 4 + ii;                                           \
        const int row = inst * 8 + l8;                                            \
        const unsigned short* srcA = Ab + (size_t)row * KK + k0_ + sgrp * 8;      \
        __builtin_amdgcn_global_load_lds(                                         \
            (const __attribute__((address_space(1))) void*)srcA,                  \
            (__attribute__((address_space(3))) void*)&As[BUF][inst * 512], 16, 0, 0); \
        int prow = p0 + row;                                                      \
        prow = prow < NP ? prow : NP - 1;                                         \
        const unsigned short* srcB = Bb + (size_t)prow * KK + k0_ + sgrp * 8;     \
        __builtin_amdgcn_global_load_lds(                                         \
            (const __attribute__((address_space(1))) void*)srcB,                  \
            (__attribute__((address_space(3))) void*)&Bs[BUF][inst * 512], 16, 0, 0); \
    }                                                                             \
} while (0)

#define COMPUTE(BUF) do {                                                         \
    _Pragma("unroll")                                                             \
    for (int kk = 0; kk < 2; ++kk) {                                              \
        short8 a[4], bfr[4];                                                      \
        const int g8 = (((kk * 4) + (lane >> 4)) ^ (lane & 7)) << 3;              \
        const int rA = wr * 64 + (lane & 15);                                     \
        const int rB = wc * 64 + (lane & 15);                                     \
        _Pragma("unroll")                                                         \
        for (int m = 0; m < 4; ++m)                                               \
            a[m] = *(const short8*)&As[BUF][(rA + m * 16) * 64 + g8];             \
        _Pragma("unroll")                                                         \
        for (int n = 0; n < 4; ++n)                                               \
            bfr[n] = *(const short8*)&Bs[BUF][(rB + n * 16) * 64 + g8];           \
        _Pragma("unroll")                                                         \
        for (int m = 0; m < 4; ++m)                                               \
            _Pragma("unroll")                                                     \
            for (int n = 0; n < 4; ++n)                                           \
                acc[m][n] = __builtin_amdgcn_mfma_f32_16x16x32_bf16(              \
                    a[m], bfr[n], acc[m][n], 0, 0, 0);                            \
    }                                                                             \
} while (0)

    STAGE(0, 0);                         // 8 loads in flight per wave

#pragma unroll 1
    for (int kt = 0; kt < 35; ++kt) {
        STAGE((kt + 1) & 1, kt + 1);     // +8 loads -> 16 in flight
        // wait ONLY for tile kt's 8 loads; kt+1's stay in flight across barrier
        asm volatile("s_waitcnt vmcnt(8)" ::: "memory");
        __builtin_amdgcn_sched_barrier(0);
        __builtin_amdgcn_s_barrier();    // all waves' tile-kt loads landed
        COMPUTE(kt & 1);
        __builtin_amdgcn_s_barrier();    // readers done before next STAGE overwrites
    }
    asm volatile("s_waitcnt vmcnt(0)" ::: "memory");
    __builtin_amdgcn_sched_barrier(0);
    __builtin_amdgcn_s_barrier();
    COMPUTE(35 & 1);

#undef STAGE
#undef COMPUTE

    float* ob = out + ((size_t)mimg * OCH + g * OUTG) * NP;
    const int o0 = m0 + wr * 64 + ((lane >> 4) << 2);
    const int pc = p0 + wc * 64 + (lane & 15);
#pragma unroll
    for (int n = 0; n < 4; ++n) {
        int p = pc + n * 16;
        if (p >= NP) continue;
#pragma unroll
        for (int m = 0; m < 4; ++m) {
#pragma unroll
            for (int r = 0; r < 4; ++r)
                ob[(size_t)(o0 + m * 16 + r) * NP + p] = acc[m][n][r];
        }
    }
}

extern "C" void kernel_launch(void* const* d_in, const int* in_sizes, int n_in,
                              void* d_out, int out_size, void* d_ws, size_t ws_size,
                              hipStream_t stream) {
    const float* x   = (const float*)d_in[0];
    const float* tf  = (const float*)d_in[1];
    const float* off = (const float*)d_in[2];
    float* out = (float*)d_out;

    unsigned short* xt  = (unsigned short*)d_ws;                    // [16][1296][2304] bf16
    unsigned short* wbf = xt + (size_t)NB * NP * KK;                // [1024][2304] bf16

    hipLaunchKernelGGL(cvt_filter, dim3(OCH), dim3(256), 0, stream, tf, wbf);
    hipLaunchKernelGGL(sample_kernel, dim3(NB * HH * 2), dim3(256), 0, stream, x, off, xt);
    hipLaunchKernelGGL(gemm_kernel, dim3(352), dim3(256), 0, stream, wbf, xt, out);
}